// Round 9
// baseline (163.810 us; speedup 1.0000x reference)
//
#include <hip/hip_runtime.h>
#include <hip/hip_fp16.h>
#include <stdint.h>

// out[16384,1024] = fp16(x) @ (fp16(sparsify24(fp16(W))) * scale -> fp16) + bias
#define M_TOT 16384
#define N_TOT 1024
#define K_TOT 1024

typedef _Float16 f16x8 __attribute__((ext_vector_type(8)));
typedef float f32x4 __attribute__((ext_vector_type(4)));
typedef unsigned short ushort4v __attribute__((ext_vector_type(4)));

// async global->LDS DMA, 16B per lane. LDS dest must be wave-uniform base + lane*16.
__device__ inline void gl2lds16(const void* g, void* l) {
    __builtin_amdgcn_global_load_lds(
        (const __attribute__((address_space(1))) void*)(uintptr_t)(g),
        (__attribute__((address_space(3))) void*)(uint32_t)(uintptr_t)(l),
        16, 0, 0);
}

// --- Kernel 1: weight prep only (verified r7). x is consumed as fp32 by the GEMM now.
// W[K][N] fp32 -> fp16 -> 2:4 sparsify along N (groups of 4) * scale -> wT[N][K] fp16
__global__ void __launch_bounds__(256) prep_w(const float* __restrict__ W,
                                              const float* __restrict__ scale_p,
                                              _Float16* __restrict__ wT) {
    const int tid = threadIdx.x;
    __shared__ _Float16 sT[64 * 68 + 4];   // sT[n][k], stride 68 (pad)
    const float scale = scale_p[0];
    const int k0 = (blockIdx.x & 15) * 64;
    const int n0 = (blockIdx.x >> 4) * 64;
    const int r = tid >> 4;            // 0..15
    const int c4 = (tid & 15) * 4;     // one 2:4 group = one float4
#pragma unroll
    for (int p = 0; p < 4; ++p) {
        const int k = p * 16 + r;
        float4 w4 = *(const float4*)&W[(size_t)(k0 + k) * N_TOT + n0 + c4];
        _Float16 h0 = (_Float16)w4.x, h1 = (_Float16)w4.y, h2 = (_Float16)w4.z, h3 = (_Float16)w4.w;
        float a0 = fabsf((float)h0), a1 = fabsf((float)h1), a2 = fabsf((float)h2), a3 = fabsf((float)h3);
        float lo01 = fminf(a0, a1), hi01 = fmaxf(a0, a1);
        float lo23 = fminf(a2, a3), hi23 = fmaxf(a2, a3);
        float s2 = fmaxf(fminf(hi01, hi23), fmaxf(lo01, lo23));
        sT[(c4 + 0) * 68 + k] = (_Float16)(((a0 >= s2) ? (float)h0 : 0.0f) * scale);
        sT[(c4 + 1) * 68 + k] = (_Float16)(((a1 >= s2) ? (float)h1 : 0.0f) * scale);
        sT[(c4 + 2) * 68 + k] = (_Float16)(((a2 >= s2) ? (float)h2 : 0.0f) * scale);
        sT[(c4 + 3) * 68 + k] = (_Float16)(((a3 >= s2) ? (float)h3 : 0.0f) * scale);
    }
    __syncthreads();
#pragma unroll
    for (int p = 0; p < 4; ++p) {
        const int n = p * 16 + r;
        ushort4v v = *(const ushort4v*)&sT[n * 68 + c4];
        *(ushort4v*)&wT[(size_t)(n0 + n) * K_TOT + k0 + c4] = v;
    }
}

// --- Kernel 2: r3's verified 256x256 / 8-wave / 3-buffer / 1-barrier-per-phase GEMM,
// single change: A staged as FP32 directly from X via gl2lds (DMA async, no store-path
// work -- unlike r7's failed reg-staging), converted fp32->fp16 on the READ path
// (2x ds_read_b128 + 8 cvts per fragment; VALU has 87% headroom at VALUBusy=13%).
// Deletes the 96 MB xh round-trip (prep 21us -> 3us).
// A-LDS: 128B rows (32 fp32, 8 x 16B slots). Swizzle: stage thread (row r, slot s8)
// pre-swizzles global k-group g8 = s8 ^ (r&7) (r-invariant mod 64); read slot for
// k-half h: (2*quad+h) ^ (l16&7) -> 64 lanes cover each slot exactly 8x = the 8cyc
// b128 floor, no excess conflict. B path / schedule / epilogue / K-order verbatim r3.
// vmcnt: 6 loads/tile (4A+2B), depth-2 prefetch -> wait vmcnt(6), never 0 mid-loop.
__global__ void __launch_bounds__(512, 2) gemm_bt(const float* __restrict__ X,
                                                  const _Float16* __restrict__ Bt,
                                                  const float* __restrict__ bias,
                                                  float* __restrict__ C) {
    __shared__ __align__(16) float     sA[3][256 * 32];   // 96 KiB (fp32 A)
    __shared__ __align__(16) _Float16  sB[3][256 * 32];   // 48 KiB (fp16 B)

    const int tid = threadIdx.x;
    const int id = blockIdx.x;
    const int by = id & 63;             // M tile 0..63 (by%8 = XCD; A-panel sharers co-XCD)
    const int bx = id >> 6;             // N tile 0..3
    const int wave = tid >> 6;          // 0..7
    const int lane = tid & 63;
    const int wm = wave >> 2;           // 0..1 -> M half (128 rows)
    const int wn = wave & 3;            // 0..3 -> N quarter (64 cols)
    const int quad = lane >> 4;
    const int l16 = lane & 15;

    // A staging (fp32): 512 threads cover 64 rows x 128B per gl2lds; 4 per 256x32 tile
    const int r0a = tid >> 3;           // 0..63
    const int s8 = tid & 7;             // 16B slot (4 fp32) within 128B row
    const int g8 = s8 ^ (r0a & 7);      // pre-swizzled global k-group (inv under r+=64)
    const float* gXs = X + (size_t)(by * 256 + r0a) * K_TOT + g8 * 4;
    const int dstA = r0a * 32 + s8 * 4;     // float elems; byte off == tid*16 (DMA-legal)

    // B staging (verbatim r3): 512 threads cover 128 rows x 64B per gl2lds
    const int row0 = tid >> 2;          // 0..127
    const int s4 = tid & 3;
    const int g = s4 ^ ((row0 >> 1) & 3);
    const _Float16* gB = Bt + (size_t)(bx * 256 + row0) * K_TOT + g * 8;
    const int dstB = row0 * 32 + s4 * 8;    // f16 elems; byte off == tid*16

    // read side. B (verbatim r3): slot = quad ^ ((l16>>1)&3), rows 64B.
    const int rdoffB = l16 * 64 + ((quad ^ ((l16 >> 1) & 3)) << 4);
    // A (fp32, 128B rows): k-half h at phys slot (2q+h)^(l16&7).
    const int e = l16 & 7;
    const int rdA0 = l16 * 128 + (((2 * quad)     ^ e) << 4);
    const int rdA1 = l16 * 128 + (((2 * quad + 1) ^ e) << 4);

    f32x4 acc[8][4];
#pragma unroll
    for (int i = 0; i < 8; ++i)
#pragma unroll
        for (int j = 0; j < 4; ++j)
            acc[i][j] = (f32x4){0.f, 0.f, 0.f, 0.f};
    f16x8 fa[8], fb[4];

#define STAGE(t, b) do {                                                    \
        const float* sa_ = gXs + (size_t)(t) * 32;                          \
        gl2lds16(sa_,                        &sA[b][dstA]);                 \
        gl2lds16(sa_ + (size_t)64 * K_TOT,   &sA[b][dstA + 64 * 32]);       \
        gl2lds16(sa_ + (size_t)128 * K_TOT,  &sA[b][dstA + 128 * 32]);      \
        gl2lds16(sa_ + (size_t)192 * K_TOT,  &sA[b][dstA + 192 * 32]);      \
        const _Float16* sb_ = gB + (size_t)(t) * 32;                        \
        gl2lds16(sb_, &sB[b][dstB]);                                        \
        gl2lds16(sb_ + (size_t)128 * K_TOT, &sB[b][dstB + 128 * 32]);       \
    } while (0)
#define FENCE asm volatile("" ::: "memory")

    // phase u: wait tile u's 6 loads; barrier; stage tile u+2 -> buf (u+2)%3;
    // ds_read B + (A fp32 -> cvt fp16); 32 MFMA. Race audit carries from r3 verbatim.
#define PH(b, t2, b2, DO_STAGE, WLAST) do {                                        \
        if (WLAST) asm volatile("s_waitcnt vmcnt(0)" ::: "memory");                \
        else       asm volatile("s_waitcnt vmcnt(6)" ::: "memory");                \
        __builtin_amdgcn_sched_barrier(0);                                         \
        __builtin_amdgcn_s_barrier();                                              \
        FENCE;                                                                     \
        if (DO_STAGE) STAGE(t2, b2);                                               \
        {                                                                          \
            const char* bB_ = (const char*)&sB[b][0] + rdoffB + wn * 4096;         \
            _Pragma("unroll")                                                      \
            for (int j = 0; j < 4; ++j) fb[j] = *(const f16x8*)(bB_ + j * 1024);   \
            const char* bA_ = (const char*)&sA[b][0] + wm * 16384;                 \
            _Pragma("unroll")                                                      \
            for (int i = 0; i < 8; ++i) {                                          \
                f32x4 u0 = *(const f32x4*)(bA_ + i * 2048 + rdA0);                 \
                f32x4 u1 = *(const f32x4*)(bA_ + i * 2048 + rdA1);                 \
                f16x8 t_;                                                          \
                t_[0] = (_Float16)u0[0]; t_[1] = (_Float16)u0[1];                  \
                t_[2] = (_Float16)u0[2]; t_[3] = (_Float16)u0[3];                  \
                t_[4] = (_Float16)u1[0]; t_[5] = (_Float16)u1[1];                  \
                t_[6] = (_Float16)u1[2]; t_[7] = (_Float16)u1[3];                  \
                fa[i] = t_;                                                        \
            }                                                                      \
        }                                                                          \
        __builtin_amdgcn_s_setprio(1);                                             \
        _Pragma("unroll")                                                          \
        for (int i = 0; i < 8; ++i) {                                              \
            _Pragma("unroll")                                                      \
            for (int j = 0; j < 4; ++j)                                            \
                acc[i][j] = __builtin_amdgcn_mfma_f32_16x16x32_f16(                \
                    fa[i], fb[j], acc[i][j], 0, 0, 0);                             \
        }                                                                          \
        __builtin_amdgcn_s_setprio(0);                                             \
    } while (0)

    // prologue: tiles 0 and 1 in flight (12 loads)
    STAGE(0, 0);
    STAGE(1, 1);

    // phases 0..29: read tile u from buf u%3, stage tile u+2 into buf (u+2)%3
    for (int it = 0; it < 10; ++it) {
        const int t = 3 * it;
        PH(0, t + 2, 2, 1, 0);
        PH(1, t + 3, 0, 1, 0);
        PH(2, t + 4, 1, 1, 0);
    }
    PH(0, 0, 0, 0, 0);   // phase 30: tile 30, no stage, vmcnt(6) retires tile 30
    PH(1, 0, 0, 0, 1);   // phase 31: tile 31, no stage, vmcnt(0)

    // epilogue (verbatim r3): D row = quad*4 + r (M), col = l16 (N); bias add
#pragma unroll
    for (int j = 0; j < 4; ++j) {
        const int col = bx * 256 + wn * 64 + j * 16 + l16;
        const float bj = bias[col];
#pragma unroll
        for (int mi = 0; mi < 8; ++mi) {
            const int row0o = by * 256 + wm * 128 + mi * 16 + quad * 4;
#pragma unroll
            for (int r = 0; r < 4; ++r) {
                C[(size_t)(row0o + r) * N_TOT + col] = acc[mi][j][r] + bj;
            }
        }
    }

#undef PH
#undef FENCE
#undef STAGE
}

extern "C" void kernel_launch(void* const* d_in, const int* in_sizes, int n_in,
                              void* d_out, int out_size, void* d_ws, size_t ws_size,
                              hipStream_t stream) {
    const float* x      = (const float*)d_in[0];   // [4,4096,1024] fp32
    const float* weight = (const float*)d_in[1];   // [1024,1024] fp32
    const float* bias   = (const float*)d_in[2];   // [1024] fp32
    const float* sscale = (const float*)d_in[3];   // [1] fp32
    float* out = (float*)d_out;

    _Float16* wT = (_Float16*)d_ws;                // 2 MiB

    prep_w<<<256, 256, 0, stream>>>(weight, sscale, wT);
    gemm_bt<<<256, 512, 0, stream>>>(x, wT, bias, out);
}